// Round 1
// baseline (765.953 us; speedup 1.0000x reference)
//
#include <hip/hip_runtime.h>

#define N_NODES 100000
#define N_EDGES 1600000
#define F_IN 256
#define HD1 128   // HEADS*HID
#define HEADS 8
#define HID 16
#define NC 16
#define NEG_SLOPE 0.2f

__device__ __forceinline__ float leaky(float x){ return x > 0.f ? x : NEG_SLOPE * x; }

// ---------------- CSR build ----------------

__global__ void __launch_bounds__(256) k_zero(int* deg){
    int i = blockIdx.x * 256 + threadIdx.x;
    if (i < N_NODES) deg[i] = 0;
}

__global__ void __launch_bounds__(256) k_count(const int* __restrict__ dst, int* __restrict__ deg){
    int i = blockIdx.x * 256 + threadIdx.x;
    if (i < N_EDGES) atomicAdd(&deg[dst[i]], 1);
}

#define SCAN_CHUNK 1024
#define SCAN_P ((N_NODES + SCAN_CHUNK - 1) / SCAN_CHUNK)   // 98

__global__ void __launch_bounds__(256) k_scan_partial(const int* __restrict__ deg, int* __restrict__ part){
    __shared__ int red[256];
    int t = threadIdx.x;
    int base = blockIdx.x * SCAN_CHUNK;
    int s = 0;
    for (int i = t; i < SCAN_CHUNK; i += 256){
        int idx = base + i;
        if (idx < N_NODES) s += deg[idx];
    }
    red[t] = s; __syncthreads();
    for (int o = 128; o > 0; o >>= 1){
        if (t < o) red[t] += red[t + o];
        __syncthreads();
    }
    if (t == 0) part[blockIdx.x] = red[0];
}

__global__ void __launch_bounds__(128) k_scan_mid(const int* __restrict__ part, int* __restrict__ pprefix, int* __restrict__ off){
    __shared__ int sd[128];
    int t = threadIdx.x;
    int v = (t < SCAN_P) ? part[t] : 0;
    sd[t] = v; __syncthreads();
    for (int o = 1; o < 128; o <<= 1){
        int add = (t >= o) ? sd[t - o] : 0;
        __syncthreads();
        sd[t] += add;
        __syncthreads();
    }
    if (t < SCAN_P) pprefix[t] = sd[t] - v;   // exclusive prefix of block totals
    if (t == 0) off[N_NODES] = N_EDGES;
}

__global__ void __launch_bounds__(256) k_scan_write(const int* __restrict__ deg, const int* __restrict__ pprefix,
                                                    int* __restrict__ off, int* __restrict__ cursor){
    __shared__ int sd[256];
    int t = threadIdx.x;
    int base = blockIdx.x * SCAN_CHUNK + t * 4;
    int v0 = 0, v1 = 0, v2 = 0, v3 = 0;
    if (base + 0 < N_NODES) v0 = deg[base + 0];
    if (base + 1 < N_NODES) v1 = deg[base + 1];
    if (base + 2 < N_NODES) v2 = deg[base + 2];
    if (base + 3 < N_NODES) v3 = deg[base + 3];
    int tsum = v0 + v1 + v2 + v3;
    sd[t] = tsum; __syncthreads();
    for (int o = 1; o < 256; o <<= 1){
        int add = (t >= o) ? sd[t - o] : 0;
        __syncthreads();
        sd[t] += add;
        __syncthreads();
    }
    int tpre = sd[t] - tsum + pprefix[blockIdx.x];
    int e0 = tpre, e1 = e0 + v0, e2 = e1 + v1, e3 = e2 + v2;
    if (base + 0 < N_NODES){ off[base + 0] = e0; cursor[base + 0] = e0; }
    if (base + 1 < N_NODES){ off[base + 1] = e1; cursor[base + 1] = e1; }
    if (base + 2 < N_NODES){ off[base + 2] = e2; cursor[base + 2] = e2; }
    if (base + 3 < N_NODES){ off[base + 3] = e3; cursor[base + 3] = e3; }
}

__global__ void __launch_bounds__(256) k_scatter(const int* __restrict__ src, const int* __restrict__ dst,
                                                  int* __restrict__ cursor, int* __restrict__ csr_src){
    int i = blockIdx.x * 256 + threadIdx.x;
    if (i < N_EDGES){
        int p = atomicAdd(&cursor[dst[i]], 1);
        csr_src[p] = src[i];
    }
}

// ---------------- GEMM1: h1 = feat @ W1, fused el1/er1 ----------------
// W1 (256x128 = 128KB) fully resident in LDS. 4 waves/block, 4 rows/wave, 2 cols/lane.

__global__ void __launch_bounds__(256) k_gemm1(const float* __restrict__ feat, const float* __restrict__ W1,
                                               const float* __restrict__ al1, const float* __restrict__ ar1,
                                               float* __restrict__ h1, float* __restrict__ el1, float* __restrict__ er1){
    __shared__ float sW[F_IN * HD1];   // 32768 floats = 128 KB
    int t = threadIdx.x;
    for (int i = t; i < (F_IN * HD1) / 4; i += 256)
        ((float4*)sW)[i] = ((const float4*)W1)[i];
    __syncthreads();

    int wid = t >> 6, lane = t & 63;
    int c0 = lane * 2;
    float a0 = al1[c0], a1 = al1[c0 + 1];
    float r0 = ar1[c0], r1 = ar1[c0 + 1];

    for (int g = blockIdx.x; g * 16 < N_NODES; g += gridDim.x){
        int rowb = g * 16 + wid * 4;
        float acc[4][2] = {{0.f,0.f},{0.f,0.f},{0.f,0.f},{0.f,0.f}};
        const float* f0 = feat + (size_t)(rowb + 0) * F_IN;
        const float* f1 = feat + (size_t)(rowb + 1) * F_IN;
        const float* f2 = feat + (size_t)(rowb + 2) * F_IN;
        const float* f3 = feat + (size_t)(rowb + 3) * F_IN;
        for (int k = 0; k < F_IN; k += 4){
            float4 xv[4];
            xv[0] = *(const float4*)(f0 + k);
            xv[1] = *(const float4*)(f1 + k);
            xv[2] = *(const float4*)(f2 + k);
            xv[3] = *(const float4*)(f3 + k);
            const float* xs = (const float*)xv;
            #pragma unroll
            for (int kk = 0; kk < 4; kk++){
                float2 wv = *(const float2*)(sW + (k + kk) * HD1 + c0);
                #pragma unroll
                for (int r = 0; r < 4; r++){
                    acc[r][0] += xs[r * 4 + kk] * wv.x;
                    acc[r][1] += xs[r * 4 + kk] * wv.y;
                }
            }
        }
        #pragma unroll
        for (int r = 0; r < 4; r++){
            int row = rowb + r;
            *(float2*)(h1 + (size_t)row * HD1 + c0) = make_float2(acc[r][0], acc[r][1]);
            float pe = acc[r][0] * a0 + acc[r][1] * a1;
            float pr = acc[r][0] * r0 + acc[r][1] * r1;
            pe += __shfl_xor(pe, 1); pe += __shfl_xor(pe, 2); pe += __shfl_xor(pe, 4);
            pr += __shfl_xor(pr, 1); pr += __shfl_xor(pr, 2); pr += __shfl_xor(pr, 4);
            if ((lane & 7) == 0){
                int h = lane >> 3;
                el1[row * HEADS + h] = pe;
                er1[row * HEADS + h] = pr;
            }
        }
    }
}

// ---------------- Layer-1 aggregation: one wave per dst node ----------------

__global__ void __launch_bounds__(256) k_agg1(const int* __restrict__ off, const int* __restrict__ csr_src,
                                              const float* __restrict__ el1, const float* __restrict__ er1,
                                              const float* __restrict__ h1, const float* __restrict__ b1,
                                              float* __restrict__ x2){
    int wid = threadIdx.x >> 6, lane = threadIdx.x & 63;
    int n = blockIdx.x * 4 + wid;
    if (n >= N_NODES) return;
    int jb = off[n], je = off[n + 1];
    int c0 = lane * 2;
    float erh = (lane < HEADS) ? er1[n * HEADS + lane] : 0.f;
    float acc0 = 0.f, acc1 = 0.f, wsum = 0.f;
    for (int j = jb; j < je; ++j){
        int s = csr_src[j];
        float w = 0.f;
        if (lane < HEADS){
            float e = el1[s * HEADS + lane] + erh;
            w = __expf(leaky(e));
            wsum += w;
        }
        float ww = __shfl(w, lane >> 3);
        float2 hv = *(const float2*)(h1 + (size_t)s * HD1 + c0);
        acc0 += ww * hv.x;
        acc1 += ww * hv.y;
    }
    float ws = __shfl(wsum, lane >> 3);
    float o0 = 0.f, o1 = 0.f;
    if (je > jb){ o0 = acc0 / ws; o1 = acc1 / ws; }
    o0 += b1[c0]; o1 += b1[c0 + 1];
    o0 = o0 > 0.f ? o0 : __expf(o0) - 1.f;   // ELU
    o1 = o1 > 0.f ? o1 : __expf(o1) - 1.f;
    *(float2*)(x2 + (size_t)n * HD1 + c0) = make_float2(o0, o1);
}

// ---------------- GEMM2: h2 = x2 @ W2, fused el2/er2 ----------------

__global__ void __launch_bounds__(256) k_gemm2(const float* __restrict__ x2, const float* __restrict__ W2,
                                               const float* __restrict__ al2, const float* __restrict__ ar2,
                                               float* __restrict__ h2, float* __restrict__ el2, float* __restrict__ er2){
    __shared__ float sW[HD1 * NC];   // 8 KB
    __shared__ float sX[16 * HD1];   // 8 KB
    int t = threadIdx.x;
    for (int i = t; i < (HD1 * NC) / 4; i += 256)
        ((float4*)sW)[i] = ((const float4*)W2)[i];
    int r = t >> 4, c = t & 15;
    float a2 = al2[c], r2 = ar2[c];
    for (int g = blockIdx.x; g * 16 < N_NODES; g += gridDim.x){
        int rowb = g * 16;
        __syncthreads();
        for (int i = t; i < (16 * HD1) / 4; i += 256)
            ((float4*)sX)[i] = ((const float4*)(x2 + (size_t)rowb * HD1))[i];
        __syncthreads();
        float acc = 0.f;
        #pragma unroll 8
        for (int k = 0; k < HD1; k++)
            acc += sX[r * HD1 + k] * sW[k * NC + c];
        int row = rowb + r;
        h2[row * NC + c] = acc;
        float pe = acc * a2, pr = acc * r2;
        #pragma unroll
        for (int d = 1; d < 16; d <<= 1){ pe += __shfl_xor(pe, d); pr += __shfl_xor(pr, d); }
        if (c == 0){ el2[row] = pe; er2[row] = pr; }
    }
}

// ---------------- Layer-2 aggregation + bias + log_softmax ----------------

__global__ void __launch_bounds__(256) k_agg2(const int* __restrict__ off, const int* __restrict__ csr_src,
                                              const float* __restrict__ el2, const float* __restrict__ er2,
                                              const float* __restrict__ h2, const float* __restrict__ b2,
                                              float* __restrict__ out){
    int t = threadIdx.x;
    int sub = t >> 4;          // 16 nodes per block
    int c = t & 15;
    int n = blockIdx.x * 16 + sub;
    if (n >= N_NODES) return;
    int jb = off[n], je = off[n + 1];
    float er = er2[n];
    float acc = 0.f, wsum = 0.f;
    for (int j = jb; j < je; ++j){
        int s = csr_src[j];
        float w = __expf(leaky(el2[s] + er));
        wsum += w;
        acc += w * h2[(size_t)s * NC + c];
    }
    float o = (je > jb) ? acc / wsum : 0.f;
    o += b2[c];
    // log_softmax over the 16 classes (16-lane group)
    float m = o;
    #pragma unroll
    for (int d = 1; d < 16; d <<= 1) m = fmaxf(m, __shfl_xor(m, d));
    float ex = __expf(o - m);
    #pragma unroll
    for (int d = 1; d < 16; d <<= 1) ex += __shfl_xor(ex, d);
    out[(size_t)n * NC + c] = o - m - __logf(ex);
}

// ---------------- launch ----------------

extern "C" void kernel_launch(void* const* d_in, const int* in_sizes, int n_in,
                              void* d_out, int out_size, void* d_ws, size_t ws_size,
                              hipStream_t stream){
    const float* feat = (const float*)d_in[0];
    const int*   src  = (const int*)d_in[1];
    const int*   dst  = (const int*)d_in[2];
    const float* W1   = (const float*)d_in[3];
    const float* al1  = (const float*)d_in[4];
    const float* ar1  = (const float*)d_in[5];
    const float* b1   = (const float*)d_in[6];
    const float* W2   = (const float*)d_in[7];
    const float* al2  = (const float*)d_in[8];
    const float* ar2  = (const float*)d_in[9];
    const float* b2   = (const float*)d_in[10];
    float* out = (float*)d_out;

    char* w = (char*)d_ws;
    auto alloc = [&](size_t bytes) -> char* {
        char* p = w;
        w += (bytes + 255) & ~(size_t)255;
        return p;
    };
    int*   deg     = (int*)alloc((size_t)N_NODES * 4);
    int*   off     = (int*)alloc((size_t)(N_NODES + 1) * 4);
    int*   cursor  = (int*)alloc((size_t)N_NODES * 4);
    int*   part    = (int*)alloc((size_t)SCAN_P * 4);
    int*   pprefix = (int*)alloc((size_t)SCAN_P * 4);
    int*   csr_src = (int*)alloc((size_t)N_EDGES * 4);
    float* h1      = (float*)alloc((size_t)N_NODES * HD1 * 4);
    float* el1v    = (float*)alloc((size_t)N_NODES * HEADS * 4);
    float* er1v    = (float*)alloc((size_t)N_NODES * HEADS * 4);
    float* x2      = (float*)alloc((size_t)N_NODES * HD1 * 4);
    float* h2      = (float*)alloc((size_t)N_NODES * NC * 4);
    float* el2v    = (float*)alloc((size_t)N_NODES * 4);
    float* er2v    = (float*)alloc((size_t)N_NODES * 4);

    // CSR build
    k_zero<<<(N_NODES + 255) / 256, 256, 0, stream>>>(deg);
    k_count<<<(N_EDGES + 255) / 256, 256, 0, stream>>>(dst, deg);
    k_scan_partial<<<SCAN_P, 256, 0, stream>>>(deg, part);
    k_scan_mid<<<1, 128, 0, stream>>>(part, pprefix, off);
    k_scan_write<<<SCAN_P, 256, 0, stream>>>(deg, pprefix, off, cursor);
    k_scatter<<<(N_EDGES + 255) / 256, 256, 0, stream>>>(src, dst, cursor, csr_src);

    // Layer 1
    k_gemm1<<<256, 256, 0, stream>>>(feat, W1, al1, ar1, h1, el1v, er1v);
    k_agg1<<<(N_NODES + 3) / 4, 256, 0, stream>>>(off, csr_src, el1v, er1v, h1, b1, x2);

    // Layer 2
    k_gemm2<<<1024, 256, 0, stream>>>(x2, W2, al2, ar2, h2, el2v, er2v);
    k_agg2<<<(N_NODES + 15) / 16, 256, 0, stream>>>(off, csr_src, el2v, er2v, h2, b2, out);
}

// Round 2
// 601.553 us; speedup vs baseline: 1.2733x; 1.2733x over previous
//
#include <hip/hip_runtime.h>

#define N_NODES 100000
#define N_EDGES 1600000
#define F_IN 256
#define HD1 128   // HEADS*HID
#define HEADS 8
#define HID 16
#define NC 16
#define NEG_SLOPE 0.2f

__device__ __forceinline__ float leaky(float x){ return x > 0.f ? x : NEG_SLOPE * x; }

typedef __bf16 bf16x8 __attribute__((ext_vector_type(8)));
typedef short short8 __attribute__((ext_vector_type(8)));
typedef float f32x4 __attribute__((ext_vector_type(4)));

// ---------------- CSR build ----------------

__global__ void __launch_bounds__(256) k_zero(int* deg){
    int i = blockIdx.x * 256 + threadIdx.x;
    if (i < N_NODES) deg[i] = 0;
}

__global__ void __launch_bounds__(256) k_count(const int* __restrict__ dst, int* __restrict__ deg){
    int i = blockIdx.x * 256 + threadIdx.x;
    if (i < N_EDGES) atomicAdd(&deg[dst[i]], 1);
}

#define SCAN_CHUNK 1024
#define SCAN_P ((N_NODES + SCAN_CHUNK - 1) / SCAN_CHUNK)   // 98

__global__ void __launch_bounds__(256) k_scan_partial(const int* __restrict__ deg, int* __restrict__ part){
    __shared__ int red[256];
    int t = threadIdx.x;
    int base = blockIdx.x * SCAN_CHUNK;
    int s = 0;
    for (int i = t; i < SCAN_CHUNK; i += 256){
        int idx = base + i;
        if (idx < N_NODES) s += deg[idx];
    }
    red[t] = s; __syncthreads();
    for (int o = 128; o > 0; o >>= 1){
        if (t < o) red[t] += red[t + o];
        __syncthreads();
    }
    if (t == 0) part[blockIdx.x] = red[0];
}

__global__ void __launch_bounds__(128) k_scan_mid(const int* __restrict__ part, int* __restrict__ pprefix, int* __restrict__ off){
    __shared__ int sd[128];
    int t = threadIdx.x;
    int v = (t < SCAN_P) ? part[t] : 0;
    sd[t] = v; __syncthreads();
    for (int o = 1; o < 128; o <<= 1){
        int add = (t >= o) ? sd[t - o] : 0;
        __syncthreads();
        sd[t] += add;
        __syncthreads();
    }
    if (t < SCAN_P) pprefix[t] = sd[t] - v;   // exclusive prefix of block totals
    if (t == 0) off[N_NODES] = N_EDGES;
}

__global__ void __launch_bounds__(256) k_scan_write(const int* __restrict__ deg, const int* __restrict__ pprefix,
                                                    int* __restrict__ off, int* __restrict__ cursor){
    __shared__ int sd[256];
    int t = threadIdx.x;
    int base = blockIdx.x * SCAN_CHUNK + t * 4;
    int v0 = 0, v1 = 0, v2 = 0, v3 = 0;
    if (base + 0 < N_NODES) v0 = deg[base + 0];
    if (base + 1 < N_NODES) v1 = deg[base + 1];
    if (base + 2 < N_NODES) v2 = deg[base + 2];
    if (base + 3 < N_NODES) v3 = deg[base + 3];
    int tsum = v0 + v1 + v2 + v3;
    sd[t] = tsum; __syncthreads();
    for (int o = 1; o < 256; o <<= 1){
        int add = (t >= o) ? sd[t - o] : 0;
        __syncthreads();
        sd[t] += add;
        __syncthreads();
    }
    int tpre = sd[t] - tsum + pprefix[blockIdx.x];
    int e0 = tpre, e1 = e0 + v0, e2 = e1 + v1, e3 = e2 + v2;
    if (base + 0 < N_NODES){ off[base + 0] = e0; cursor[base + 0] = e0; }
    if (base + 1 < N_NODES){ off[base + 1] = e1; cursor[base + 1] = e1; }
    if (base + 2 < N_NODES){ off[base + 2] = e2; cursor[base + 2] = e2; }
    if (base + 3 < N_NODES){ off[base + 3] = e3; cursor[base + 3] = e3; }
}

__global__ void __launch_bounds__(256) k_scatter(const int* __restrict__ src, const int* __restrict__ dst,
                                                  int* __restrict__ cursor, int* __restrict__ csr_src){
    int i = blockIdx.x * 256 + threadIdx.x;
    if (i < N_EDGES){
        int p = atomicAdd(&cursor[dst[i]], 1);
        csr_src[p] = src[i];
    }
}

// ---------------- W1 split (fp32 -> bf16 hi/lo), transpose + XOR-swizzle ----------------
// Output layout: WT[n][k'] where k' = k ^ ((n&7)<<3), n=0..127, k=0..255 (bf16).

__global__ void __launch_bounds__(256) k_splitW(const float* __restrict__ W1,
                                                short* __restrict__ WTH, short* __restrict__ WTL){
    int i = blockIdx.x * 256 + threadIdx.x;   // 32768 elems
    if (i >= F_IN * HD1) return;
    int k = i >> 7, n = i & 127;
    float v = W1[i];
    unsigned u = __float_as_uint(v);
    short hs = (short)(u >> 16);
    float lo = v - __uint_as_float(u & 0xffff0000u);
    short ls = (short)(__float_as_uint(lo) >> 16);
    int idx = n * 256 + (k ^ ((n & 7) << 3));
    WTH[idx] = hs;
    WTL[idx] = ls;
}

// ---------------- GEMM1 (MFMA bf16x2): h1 = feat @ W1 ----------------
// Block = 256 thr (4 waves), each wave 32 rows; block covers 128 rows x 64 cols (blockIdx.y = col half).
// LDS: W-half hi+lo = 64KB -> 2 blocks/CU.

__device__ __forceinline__ void split8(float4 f0, float4 f1, short8& h, short8& l){
    float f[8] = {f0.x, f0.y, f0.z, f0.w, f1.x, f1.y, f1.z, f1.w};
    #pragma unroll
    for (int i = 0; i < 8; i++){
        unsigned u = __float_as_uint(f[i]);
        h[i] = (short)(u >> 16);
        float lo = f[i] - __uint_as_float(u & 0xffff0000u);
        l[i] = (short)(__float_as_uint(lo) >> 16);
    }
}

__global__ void __launch_bounds__(256, 2) k_gemm1m(const float* __restrict__ feat,
                                                   const short* __restrict__ WTH, const short* __restrict__ WTL,
                                                   float* __restrict__ h1){
    __shared__ short sWH[64 * 256];
    __shared__ short sWL[64 * 256];
    int t = threadIdx.x;
    int ch = blockIdx.y;
    {
        const short8* gh = (const short8*)(WTH + (size_t)ch * 16384);
        const short8* gl = (const short8*)(WTL + (size_t)ch * 16384);
        short8* sh = (short8*)sWH;
        short8* sl = (short8*)sWL;
        for (int i = t; i < 2048; i += 256){ sh[i] = gh[i]; sl[i] = gl[i]; }
    }
    __syncthreads();

    int wid = t >> 6, lane = t & 63;
    int m16 = lane & 15, kg = lane >> 4;
    int rowb = blockIdx.x * 128 + wid * 32;

    f32x4 acc[2][4];
    #pragma unroll
    for (int a = 0; a < 2; a++)
        #pragma unroll
        for (int b = 0; b < 4; b++)
            acc[a][b] = (f32x4){0.f, 0.f, 0.f, 0.f};

    int r0 = rowb + m16;       if (r0 > N_NODES - 1) r0 = N_NODES - 1;
    int r1 = rowb + 16 + m16;  if (r1 > N_NODES - 1) r1 = N_NODES - 1;
    const float* fp0 = feat + (size_t)r0 * F_IN;
    const float* fp1 = feat + (size_t)r1 * F_IN;

    #pragma unroll
    for (int ks = 0; ks < 8; ks++){
        int kbase = ks * 32 + kg * 8;
        short8 ah[2], al[2];
        {
            const float4* p = (const float4*)(fp0 + kbase);
            split8(p[0], p[1], ah[0], al[0]);
        }
        {
            const float4* p = (const float4*)(fp1 + kbase);
            split8(p[0], p[1], ah[1], al[1]);
        }
        bf16x8 AH0 = __builtin_bit_cast(bf16x8, ah[0]);
        bf16x8 AH1 = __builtin_bit_cast(bf16x8, ah[1]);
        bf16x8 AL0 = __builtin_bit_cast(bf16x8, al[0]);
        bf16x8 AL1 = __builtin_bit_cast(bf16x8, al[1]);
        #pragma unroll
        for (int c = 0; c < 4; c++){
            int n = (c << 4) + m16;
            int kk = kbase ^ ((n & 7) << 3);
            bf16x8 bh = __builtin_bit_cast(bf16x8, *(const short8*)(sWH + n * 256 + kk));
            bf16x8 bl = __builtin_bit_cast(bf16x8, *(const short8*)(sWL + n * 256 + kk));
            acc[0][c] = __builtin_amdgcn_mfma_f32_16x16x32_bf16(AH0, bh, acc[0][c], 0, 0, 0);
            acc[1][c] = __builtin_amdgcn_mfma_f32_16x16x32_bf16(AH1, bh, acc[1][c], 0, 0, 0);
            acc[0][c] = __builtin_amdgcn_mfma_f32_16x16x32_bf16(AH0, bl, acc[0][c], 0, 0, 0);
            acc[1][c] = __builtin_amdgcn_mfma_f32_16x16x32_bf16(AH1, bl, acc[1][c], 0, 0, 0);
            acc[0][c] = __builtin_amdgcn_mfma_f32_16x16x32_bf16(AL0, bh, acc[0][c], 0, 0, 0);
            acc[1][c] = __builtin_amdgcn_mfma_f32_16x16x32_bf16(AL1, bh, acc[1][c], 0, 0, 0);
        }
    }

    #pragma unroll
    for (int rf = 0; rf < 2; rf++){
        #pragma unroll
        for (int c = 0; c < 4; c++){
            #pragma unroll
            for (int r = 0; r < 4; r++){
                int row = rowb + rf * 16 + kg * 4 + r;
                if (row < N_NODES)
                    h1[(size_t)row * HD1 + ch * 64 + c * 16 + m16] = acc[rf][c][r];
            }
        }
    }
}

// ---------------- el1/er1 from h1 ----------------

__global__ void __launch_bounds__(256) k_attn1(const float* __restrict__ h1,
                                               const float* __restrict__ al1, const float* __restrict__ ar1,
                                               float* __restrict__ el1, float* __restrict__ er1){
    int i = blockIdx.x * 256 + threadIdx.x;
    if (i >= N_NODES * HEADS) return;
    int n = i >> 3, h = i & 7;
    const float4* hp = (const float4*)(h1 + (size_t)n * HD1 + h * HID);
    const float4* ap = (const float4*)(al1 + h * HID);
    const float4* rp = (const float4*)(ar1 + h * HID);
    float pe = 0.f, pr = 0.f;
    #pragma unroll
    for (int j = 0; j < 4; j++){
        float4 v = hp[j], a = ap[j], r = rp[j];
        pe += v.x * a.x + v.y * a.y + v.z * a.z + v.w * a.w;
        pr += v.x * r.x + v.y * r.y + v.z * r.z + v.w * r.w;
    }
    el1[i] = pe;
    er1[i] = pr;
}

// ---------------- Layer-1 aggregation: one wave per dst node ----------------

__global__ void __launch_bounds__(256) k_agg1(const int* __restrict__ off, const int* __restrict__ csr_src,
                                              const float* __restrict__ el1, const float* __restrict__ er1,
                                              const float* __restrict__ h1, const float* __restrict__ b1,
                                              float* __restrict__ x2){
    int wid = threadIdx.x >> 6, lane = threadIdx.x & 63;
    int n = blockIdx.x * 4 + wid;
    if (n >= N_NODES) return;
    int jb = off[n], je = off[n + 1];
    int c0 = lane * 2;
    float erh = (lane < HEADS) ? er1[n * HEADS + lane] : 0.f;
    float acc0 = 0.f, acc1 = 0.f, wsum = 0.f;
    for (int j = jb; j < je; ++j){
        int s = csr_src[j];
        float w = 0.f;
        if (lane < HEADS){
            float e = el1[s * HEADS + lane] + erh;
            w = __expf(leaky(e));
            wsum += w;
        }
        float ww = __shfl(w, lane >> 3);
        float2 hv = *(const float2*)(h1 + (size_t)s * HD1 + c0);
        acc0 += ww * hv.x;
        acc1 += ww * hv.y;
    }
    float ws = __shfl(wsum, lane >> 3);
    float o0 = 0.f, o1 = 0.f;
    if (je > jb){ o0 = acc0 / ws; o1 = acc1 / ws; }
    o0 += b1[c0]; o1 += b1[c0 + 1];
    o0 = o0 > 0.f ? o0 : __expf(o0) - 1.f;   // ELU
    o1 = o1 > 0.f ? o1 : __expf(o1) - 1.f;
    *(float2*)(x2 + (size_t)n * HD1 + c0) = make_float2(o0, o1);
}

// ---------------- GEMM2: h2 = x2 @ W2, fused el2/er2 ----------------

__global__ void __launch_bounds__(256) k_gemm2(const float* __restrict__ x2, const float* __restrict__ W2,
                                               const float* __restrict__ al2, const float* __restrict__ ar2,
                                               float* __restrict__ h2, float* __restrict__ el2, float* __restrict__ er2){
    __shared__ float sW[HD1 * NC];   // 8 KB
    __shared__ float sX[16 * HD1];   // 8 KB
    int t = threadIdx.x;
    for (int i = t; i < (HD1 * NC) / 4; i += 256)
        ((float4*)sW)[i] = ((const float4*)W2)[i];
    int r = t >> 4, c = t & 15;
    float a2 = al2[c], r2 = ar2[c];
    for (int g = blockIdx.x; g * 16 < N_NODES; g += gridDim.x){
        int rowb = g * 16;
        __syncthreads();
        for (int i = t; i < (16 * HD1) / 4; i += 256)
            ((float4*)sX)[i] = ((const float4*)(x2 + (size_t)rowb * HD1))[i];
        __syncthreads();
        float acc = 0.f;
        #pragma unroll 8
        for (int k = 0; k < HD1; k++)
            acc += sX[r * HD1 + k] * sW[k * NC + c];
        int row = rowb + r;
        h2[row * NC + c] = acc;
        float pe = acc * a2, pr = acc * r2;
        #pragma unroll
        for (int d = 1; d < 16; d <<= 1){ pe += __shfl_xor(pe, d); pr += __shfl_xor(pr, d); }
        if (c == 0){ el2[row] = pe; er2[row] = pr; }
    }
}

// ---------------- Layer-2 aggregation + bias + log_softmax ----------------

__global__ void __launch_bounds__(256) k_agg2(const int* __restrict__ off, const int* __restrict__ csr_src,
                                              const float* __restrict__ el2, const float* __restrict__ er2,
                                              const float* __restrict__ h2, const float* __restrict__ b2,
                                              float* __restrict__ out){
    int t = threadIdx.x;
    int sub = t >> 4;          // 16 nodes per block
    int c = t & 15;
    int n = blockIdx.x * 16 + sub;
    if (n >= N_NODES) return;
    int jb = off[n], je = off[n + 1];
    float er = er2[n];
    float acc = 0.f, wsum = 0.f;
    for (int j = jb; j < je; ++j){
        int s = csr_src[j];
        float w = __expf(leaky(el2[s] + er));
        wsum += w;
        acc += w * h2[(size_t)s * NC + c];
    }
    float o = (je > jb) ? acc / wsum : 0.f;
    o += b2[c];
    // log_softmax over the 16 classes (16-lane group)
    float m = o;
    #pragma unroll
    for (int d = 1; d < 16; d <<= 1) m = fmaxf(m, __shfl_xor(m, d));
    float ex = __expf(o - m);
    #pragma unroll
    for (int d = 1; d < 16; d <<= 1) ex += __shfl_xor(ex, d);
    out[(size_t)n * NC + c] = o - m - __logf(ex);
}

// ---------------- launch ----------------

extern "C" void kernel_launch(void* const* d_in, const int* in_sizes, int n_in,
                              void* d_out, int out_size, void* d_ws, size_t ws_size,
                              hipStream_t stream){
    const float* feat = (const float*)d_in[0];
    const int*   src  = (const int*)d_in[1];
    const int*   dst  = (const int*)d_in[2];
    const float* W1   = (const float*)d_in[3];
    const float* al1  = (const float*)d_in[4];
    const float* ar1  = (const float*)d_in[5];
    const float* b1   = (const float*)d_in[6];
    const float* W2   = (const float*)d_in[7];
    const float* al2  = (const float*)d_in[8];
    const float* ar2  = (const float*)d_in[9];
    const float* b2   = (const float*)d_in[10];
    float* out = (float*)d_out;

    char* w = (char*)d_ws;
    auto alloc = [&](size_t bytes) -> char* {
        char* p = w;
        w += (bytes + 255) & ~(size_t)255;
        return p;
    };
    int*   deg     = (int*)alloc((size_t)N_NODES * 4);
    int*   off     = (int*)alloc((size_t)(N_NODES + 1) * 4);
    int*   cursor  = (int*)alloc((size_t)N_NODES * 4);
    int*   part    = (int*)alloc((size_t)SCAN_P * 4);
    int*   pprefix = (int*)alloc((size_t)SCAN_P * 4);
    int*   csr_src = (int*)alloc((size_t)N_EDGES * 4);
    float* h1      = (float*)alloc((size_t)N_NODES * HD1 * 4);
    float* el1v    = (float*)alloc((size_t)N_NODES * HEADS * 4);
    float* er1v    = (float*)alloc((size_t)N_NODES * HEADS * 4);
    float* x2      = (float*)alloc((size_t)N_NODES * HD1 * 4);
    float* h2      = (float*)alloc((size_t)N_NODES * NC * 4);
    float* el2v    = (float*)alloc((size_t)N_NODES * 4);
    float* er2v    = (float*)alloc((size_t)N_NODES * 4);
    short* WTH     = (short*)alloc((size_t)F_IN * HD1 * 2);
    short* WTL     = (short*)alloc((size_t)F_IN * HD1 * 2);

    // CSR build
    k_zero<<<(N_NODES + 255) / 256, 256, 0, stream>>>(deg);
    k_count<<<(N_EDGES + 255) / 256, 256, 0, stream>>>(dst, deg);
    k_scan_partial<<<SCAN_P, 256, 0, stream>>>(deg, part);
    k_scan_mid<<<1, 128, 0, stream>>>(part, pprefix, off);
    k_scan_write<<<SCAN_P, 256, 0, stream>>>(deg, pprefix, off, cursor);
    k_scatter<<<(N_EDGES + 255) / 256, 256, 0, stream>>>(src, dst, cursor, csr_src);

    // Layer 1
    k_splitW<<<(F_IN * HD1 + 255) / 256, 256, 0, stream>>>(W1, WTH, WTL);
    dim3 g1((N_NODES + 127) / 128, 2);
    k_gemm1m<<<g1, 256, 0, stream>>>(feat, WTH, WTL, h1);
    k_attn1<<<(N_NODES * HEADS + 255) / 256, 256, 0, stream>>>(h1, al1, ar1, el1v, er1v);
    k_agg1<<<(N_NODES + 3) / 4, 256, 0, stream>>>(off, csr_src, el1v, er1v, h1, b1, x2);

    // Layer 2
    k_gemm2<<<1024, 256, 0, stream>>>(x2, W2, al2, ar2, h2, el2v, er2v);
    k_agg2<<<(N_NODES + 15) / 16, 256, 0, stream>>>(off, csr_src, el2v, er2v, h2, b2, out);
}

// Round 3
// 470.177 us; speedup vs baseline: 1.6291x; 1.2794x over previous
//
#include <hip/hip_runtime.h>

#define N_NODES 100000
#define N_EDGES 1600000
#define F_IN 256
#define HD1 128   // HEADS*HID
#define HEADS 8
#define HID 16
#define NC 16
#define NEG_SLOPE 0.2f

__device__ __forceinline__ float leaky(float x){ return x > 0.f ? x : NEG_SLOPE * x; }
__device__ __forceinline__ unsigned short f2bf(float f){
    unsigned u = __float_as_uint(f);
    u += 0x7fff + ((u >> 16) & 1);       // round-to-nearest-even
    return (unsigned short)(u >> 16);
}
__device__ __forceinline__ float bf2f(unsigned short s){
    return __uint_as_float((unsigned)s << 16);
}

typedef __bf16 bf16x8 __attribute__((ext_vector_type(8)));
typedef short short8 __attribute__((ext_vector_type(8)));
typedef float f32x4 __attribute__((ext_vector_type(4)));

// ---------------- CSR build ----------------

__global__ void __launch_bounds__(256) k_zero(int* deg){
    int i = blockIdx.x * 256 + threadIdx.x;
    if (i < N_NODES) deg[i] = 0;
}

__global__ void __launch_bounds__(256) k_count(const int* __restrict__ dst, int* __restrict__ deg){
    int i = blockIdx.x * 256 + threadIdx.x;
    if (i < N_EDGES) atomicAdd(&deg[dst[i]], 1);
}

#define SCAN_CHUNK 1024
#define SCAN_P ((N_NODES + SCAN_CHUNK - 1) / SCAN_CHUNK)   // 98

__global__ void __launch_bounds__(256) k_scan_partial(const int* __restrict__ deg, int* __restrict__ part){
    __shared__ int red[256];
    int t = threadIdx.x;
    int base = blockIdx.x * SCAN_CHUNK;
    int s = 0;
    for (int i = t; i < SCAN_CHUNK; i += 256){
        int idx = base + i;
        if (idx < N_NODES) s += deg[idx];
    }
    red[t] = s; __syncthreads();
    for (int o = 128; o > 0; o >>= 1){
        if (t < o) red[t] += red[t + o];
        __syncthreads();
    }
    if (t == 0) part[blockIdx.x] = red[0];
}

__global__ void __launch_bounds__(128) k_scan_mid(const int* __restrict__ part, int* __restrict__ pprefix, int* __restrict__ off){
    __shared__ int sd[128];
    int t = threadIdx.x;
    int v = (t < SCAN_P) ? part[t] : 0;
    sd[t] = v; __syncthreads();
    for (int o = 1; o < 128; o <<= 1){
        int add = (t >= o) ? sd[t - o] : 0;
        __syncthreads();
        sd[t] += add;
        __syncthreads();
    }
    if (t < SCAN_P) pprefix[t] = sd[t] - v;   // exclusive prefix of block totals
    if (t == 0) off[N_NODES] = N_EDGES;
}

__global__ void __launch_bounds__(256) k_scan_write(const int* __restrict__ deg, const int* __restrict__ pprefix,
                                                    int* __restrict__ off, int* __restrict__ cursor){
    __shared__ int sd[256];
    int t = threadIdx.x;
    int base = blockIdx.x * SCAN_CHUNK + t * 4;
    int v0 = 0, v1 = 0, v2 = 0, v3 = 0;
    if (base + 0 < N_NODES) v0 = deg[base + 0];
    if (base + 1 < N_NODES) v1 = deg[base + 1];
    if (base + 2 < N_NODES) v2 = deg[base + 2];
    if (base + 3 < N_NODES) v3 = deg[base + 3];
    int tsum = v0 + v1 + v2 + v3;
    sd[t] = tsum; __syncthreads();
    for (int o = 1; o < 256; o <<= 1){
        int add = (t >= o) ? sd[t - o] : 0;
        __syncthreads();
        sd[t] += add;
        __syncthreads();
    }
    int tpre = sd[t] - tsum + pprefix[blockIdx.x];
    int e0 = tpre, e1 = e0 + v0, e2 = e1 + v1, e3 = e2 + v2;
    if (base + 0 < N_NODES){ off[base + 0] = e0; cursor[base + 0] = e0; }
    if (base + 1 < N_NODES){ off[base + 1] = e1; cursor[base + 1] = e1; }
    if (base + 2 < N_NODES){ off[base + 2] = e2; cursor[base + 2] = e2; }
    if (base + 3 < N_NODES){ off[base + 3] = e3; cursor[base + 3] = e3; }
}

__global__ void __launch_bounds__(256) k_scatter(const int* __restrict__ src, const int* __restrict__ dst,
                                                  int* __restrict__ cursor, int* __restrict__ csr_src){
    int i = blockIdx.x * 256 + threadIdx.x;
    if (i < N_EDGES){
        int p = atomicAdd(&cursor[dst[i]], 1);
        csr_src[p] = src[i];
    }
}

// ---------------- W1 split (fp32 -> bf16 hi/lo), transpose + XOR-swizzle ----------------

__global__ void __launch_bounds__(256) k_splitW(const float* __restrict__ W1,
                                                short* __restrict__ WTH, short* __restrict__ WTL){
    int i = blockIdx.x * 256 + threadIdx.x;   // 32768 elems
    if (i >= F_IN * HD1) return;
    int k = i >> 7, n = i & 127;
    float v = W1[i];
    unsigned u = __float_as_uint(v);
    short hs = (short)(u >> 16);
    float lo = v - __uint_as_float(u & 0xffff0000u);
    short ls = (short)(__float_as_uint(lo) >> 16);
    int idx = n * 256 + (k ^ ((n & 7) << 3));
    WTH[idx] = hs;
    WTL[idx] = ls;
}

// ---------------- GEMM1 (MFMA bf16x2): h1b = bf16(feat @ W1) ----------------

__device__ __forceinline__ void split8(float4 f0, float4 f1, short8& h, short8& l){
    float f[8] = {f0.x, f0.y, f0.z, f0.w, f1.x, f1.y, f1.z, f1.w};
    #pragma unroll
    for (int i = 0; i < 8; i++){
        unsigned u = __float_as_uint(f[i]);
        h[i] = (short)(u >> 16);
        float lo = f[i] - __uint_as_float(u & 0xffff0000u);
        l[i] = (short)(__float_as_uint(lo) >> 16);
    }
}

__global__ void __launch_bounds__(256, 2) k_gemm1m(const float* __restrict__ feat,
                                                   const short* __restrict__ WTH, const short* __restrict__ WTL,
                                                   unsigned short* __restrict__ h1b){
    __shared__ short sWH[64 * 256];
    __shared__ short sWL[64 * 256];
    int t = threadIdx.x;
    int ch = blockIdx.y;
    {
        const short8* gh = (const short8*)(WTH + (size_t)ch * 16384);
        const short8* gl = (const short8*)(WTL + (size_t)ch * 16384);
        short8* sh = (short8*)sWH;
        short8* sl = (short8*)sWL;
        for (int i = t; i < 2048; i += 256){ sh[i] = gh[i]; sl[i] = gl[i]; }
    }
    __syncthreads();

    int wid = t >> 6, lane = t & 63;
    int m16 = lane & 15, kg = lane >> 4;
    int rowb = blockIdx.x * 128 + wid * 32;

    f32x4 acc[2][4];
    #pragma unroll
    for (int a = 0; a < 2; a++)
        #pragma unroll
        for (int b = 0; b < 4; b++)
            acc[a][b] = (f32x4){0.f, 0.f, 0.f, 0.f};

    int r0 = rowb + m16;       if (r0 > N_NODES - 1) r0 = N_NODES - 1;
    int r1 = rowb + 16 + m16;  if (r1 > N_NODES - 1) r1 = N_NODES - 1;
    const float* fp0 = feat + (size_t)r0 * F_IN;
    const float* fp1 = feat + (size_t)r1 * F_IN;

    #pragma unroll
    for (int ks = 0; ks < 8; ks++){
        int kbase = ks * 32 + kg * 8;
        short8 ah[2], al[2];
        {
            const float4* p = (const float4*)(fp0 + kbase);
            split8(p[0], p[1], ah[0], al[0]);
        }
        {
            const float4* p = (const float4*)(fp1 + kbase);
            split8(p[0], p[1], ah[1], al[1]);
        }
        bf16x8 AH0 = __builtin_bit_cast(bf16x8, ah[0]);
        bf16x8 AH1 = __builtin_bit_cast(bf16x8, ah[1]);
        bf16x8 AL0 = __builtin_bit_cast(bf16x8, al[0]);
        bf16x8 AL1 = __builtin_bit_cast(bf16x8, al[1]);
        #pragma unroll
        for (int c = 0; c < 4; c++){
            int n = (c << 4) + m16;
            int kk = kbase ^ ((n & 7) << 3);
            bf16x8 bh = __builtin_bit_cast(bf16x8, *(const short8*)(sWH + n * 256 + kk));
            bf16x8 bl = __builtin_bit_cast(bf16x8, *(const short8*)(sWL + n * 256 + kk));
            acc[0][c] = __builtin_amdgcn_mfma_f32_16x16x32_bf16(AH0, bh, acc[0][c], 0, 0, 0);
            acc[1][c] = __builtin_amdgcn_mfma_f32_16x16x32_bf16(AH1, bh, acc[1][c], 0, 0, 0);
            acc[0][c] = __builtin_amdgcn_mfma_f32_16x16x32_bf16(AH0, bl, acc[0][c], 0, 0, 0);
            acc[1][c] = __builtin_amdgcn_mfma_f32_16x16x32_bf16(AH1, bl, acc[1][c], 0, 0, 0);
            acc[0][c] = __builtin_amdgcn_mfma_f32_16x16x32_bf16(AL0, bh, acc[0][c], 0, 0, 0);
            acc[1][c] = __builtin_amdgcn_mfma_f32_16x16x32_bf16(AL1, bh, acc[1][c], 0, 0, 0);
        }
    }

    #pragma unroll
    for (int rf = 0; rf < 2; rf++){
        #pragma unroll
        for (int c = 0; c < 4; c++){
            #pragma unroll
            for (int r = 0; r < 4; r++){
                int row = rowb + rf * 16 + kg * 4 + r;
                if (row < N_NODES)
                    h1b[(size_t)row * HD1 + ch * 64 + c * 16 + m16] = f2bf(acc[rf][c][r]);
            }
        }
    }
}

// ---------------- el1/er1 from h1b ----------------

__global__ void __launch_bounds__(256) k_attn1(const unsigned short* __restrict__ h1b,
                                               const float* __restrict__ al1, const float* __restrict__ ar1,
                                               float* __restrict__ el1, float* __restrict__ er1){
    int i = blockIdx.x * 256 + threadIdx.x;
    if (i >= N_NODES * HEADS) return;
    int n = i >> 3, h = i & 7;
    const ushort4* hp = (const ushort4*)(h1b + (size_t)n * HD1 + h * HID);
    float pe = 0.f, pr = 0.f;
    #pragma unroll
    for (int j = 0; j < 4; j++){
        ushort4 v = hp[j];
        const float4 a = ((const float4*)(al1 + h * HID))[j];
        const float4 r = ((const float4*)(ar1 + h * HID))[j];
        float x0 = bf2f(v.x), x1 = bf2f(v.y), x2 = bf2f(v.z), x3 = bf2f(v.w);
        pe += x0 * a.x + x1 * a.y + x2 * a.z + x3 * a.w;
        pr += x0 * r.x + x1 * r.y + x2 * r.z + x3 * r.w;
    }
    el1[i] = pe;
    er1[i] = pr;
}

// ---------------- Layer-1 aggregation: one wave per dst node, 2 edges/iter ----------------

__global__ void __launch_bounds__(256) k_agg1(const int* __restrict__ off, const int* __restrict__ csr_src,
                                              const float* __restrict__ el1, const float* __restrict__ er1,
                                              const unsigned short* __restrict__ h1b, const float* __restrict__ b1,
                                              unsigned short* __restrict__ x2b){
    int wid = threadIdx.x >> 6, lane = threadIdx.x & 63;
    int n = blockIdx.x * 4 + wid;
    if (n >= N_NODES) return;
    int jb = off[n], je = off[n + 1];
    int q = lane & 31;
    int half = lane >> 5;
    bool wl = (q < HEADS);
    int wsrc = (lane & 32) | (q >> 2);       // lane holding my head's weight in my half
    float erh = wl ? er1[n * HEADS + q] : 0.f;
    float acc0 = 0.f, acc1 = 0.f, acc2 = 0.f, acc3 = 0.f, wsum = 0.f;

    #pragma unroll 2
    for (int j = jb; j < je; j += 2){
        int s0 = csr_src[j];
        int j1 = (j + 1 < je) ? j + 1 : j;
        int s1 = csr_src[j1];
        int s = half ? s1 : s0;
        float w = 0.f;
        if (wl){
            float e = el1[s * HEADS + q] + erh;
            w = __expf(leaky(e));
            if (half && (j + 1 >= je)) w = 0.f;
            wsum += w;
        }
        float ww = __shfl(w, wsrc);
        ushort4 hv = *(const ushort4*)(h1b + (size_t)s * HD1 + q * 4);
        acc0 += ww * bf2f(hv.x);
        acc1 += ww * bf2f(hv.y);
        acc2 += ww * bf2f(hv.z);
        acc3 += ww * bf2f(hv.w);
    }

    // combine halves
    acc0 += __shfl_xor(acc0, 32);
    acc1 += __shfl_xor(acc1, 32);
    acc2 += __shfl_xor(acc2, 32);
    acc3 += __shfl_xor(acc3, 32);
    wsum += __shfl_xor(wsum, 32);
    float ws = __shfl(wsum, q >> 2);         // totals live in lanes 0..7

    if (half == 0){
        float o0 = 0.f, o1 = 0.f, o2 = 0.f, o3 = 0.f;
        if (je > jb){ o0 = acc0 / ws; o1 = acc1 / ws; o2 = acc2 / ws; o3 = acc3 / ws; }
        float4 bv = *(const float4*)(b1 + q * 4);
        o0 += bv.x; o1 += bv.y; o2 += bv.z; o3 += bv.w;
        o0 = o0 > 0.f ? o0 : __expf(o0) - 1.f;
        o1 = o1 > 0.f ? o1 : __expf(o1) - 1.f;
        o2 = o2 > 0.f ? o2 : __expf(o2) - 1.f;
        o3 = o3 > 0.f ? o3 : __expf(o3) - 1.f;
        ushort4 ov = { f2bf(o0), f2bf(o1), f2bf(o2), f2bf(o3) };
        *(ushort4*)(x2b + (size_t)n * HD1 + q * 4) = ov;
    }
}

// ---------------- GEMM2: h2b = bf16(x2 @ W2), fused el2/er2 ----------------

__global__ void __launch_bounds__(256) k_gemm2(const unsigned short* __restrict__ x2b, const float* __restrict__ W2,
                                               const float* __restrict__ al2, const float* __restrict__ ar2,
                                               unsigned short* __restrict__ h2b, float* __restrict__ el2, float* __restrict__ er2){
    __shared__ float sW[HD1 * NC];   // 8 KB
    __shared__ float sX[16 * HD1];   // 8 KB
    int t = threadIdx.x;
    for (int i = t; i < (HD1 * NC) / 4; i += 256)
        ((float4*)sW)[i] = ((const float4*)W2)[i];
    int r = t >> 4, c = t & 15;
    float a2 = al2[c], r2 = ar2[c];
    for (int g = blockIdx.x; g * 16 < N_NODES; g += gridDim.x){
        int rowb = g * 16;
        __syncthreads();
        {
            ushort4 v = ((const ushort4*)(x2b + (size_t)rowb * HD1))[t * 2];
            ushort4 v2 = ((const ushort4*)(x2b + (size_t)rowb * HD1))[t * 2 + 1];
            float4 f0 = { bf2f(v.x), bf2f(v.y), bf2f(v.z), bf2f(v.w) };
            float4 f1 = { bf2f(v2.x), bf2f(v2.y), bf2f(v2.z), bf2f(v2.w) };
            ((float4*)sX)[t * 2] = f0;
            ((float4*)sX)[t * 2 + 1] = f1;
        }
        __syncthreads();
        float acc = 0.f;
        #pragma unroll 8
        for (int k = 0; k < HD1; k++)
            acc += sX[r * HD1 + k] * sW[k * NC + c];
        int row = rowb + r;
        h2b[row * NC + c] = f2bf(acc);
        float pe = acc * a2, pr = acc * r2;
        #pragma unroll
        for (int d = 1; d < 16; d <<= 1){ pe += __shfl_xor(pe, d); pr += __shfl_xor(pr, d); }
        if (c == 0){ el2[row] = pe; er2[row] = pr; }
    }
}

// ---------------- Layer-2 aggregation + bias + log_softmax ----------------

__global__ void __launch_bounds__(256) k_agg2(const int* __restrict__ off, const int* __restrict__ csr_src,
                                              const float* __restrict__ el2, const float* __restrict__ er2,
                                              const unsigned short* __restrict__ h2b, const float* __restrict__ b2,
                                              float* __restrict__ out){
    int t = threadIdx.x;
    int sub = t >> 4;          // 16 nodes per block
    int c = t & 15;
    int n = blockIdx.x * 16 + sub;
    if (n >= N_NODES) return;
    int jb = off[n], je = off[n + 1];
    float er = er2[n];
    float accA = 0.f, accB = 0.f, wsA = 0.f, wsB = 0.f;
    int j = jb;
    for (; j + 1 < je; j += 2){
        int s0 = csr_src[j];
        int s1 = csr_src[j + 1];
        float w0 = __expf(leaky(el2[s0] + er));
        float w1 = __expf(leaky(el2[s1] + er));
        float v0 = bf2f(h2b[(size_t)s0 * NC + c]);
        float v1 = bf2f(h2b[(size_t)s1 * NC + c]);
        wsA += w0; accA += w0 * v0;
        wsB += w1; accB += w1 * v1;
    }
    if (j < je){
        int s0 = csr_src[j];
        float w0 = __expf(leaky(el2[s0] + er));
        wsA += w0; accA += w0 * bf2f(h2b[(size_t)s0 * NC + c]);
    }
    float acc = accA + accB, wsum = wsA + wsB;
    float o = (je > jb) ? acc / wsum : 0.f;
    o += b2[c];
    // log_softmax over the 16 classes (16-lane group)
    float m = o;
    #pragma unroll
    for (int d = 1; d < 16; d <<= 1) m = fmaxf(m, __shfl_xor(m, d));
    float ex = __expf(o - m);
    #pragma unroll
    for (int d = 1; d < 16; d <<= 1) ex += __shfl_xor(ex, d);
    out[(size_t)n * NC + c] = o - m - __logf(ex);
}

// ---------------- launch ----------------

extern "C" void kernel_launch(void* const* d_in, const int* in_sizes, int n_in,
                              void* d_out, int out_size, void* d_ws, size_t ws_size,
                              hipStream_t stream){
    const float* feat = (const float*)d_in[0];
    const int*   src  = (const int*)d_in[1];
    const int*   dst  = (const int*)d_in[2];
    const float* W1   = (const float*)d_in[3];
    const float* al1  = (const float*)d_in[4];
    const float* ar1  = (const float*)d_in[5];
    const float* b1   = (const float*)d_in[6];
    const float* W2   = (const float*)d_in[7];
    const float* al2  = (const float*)d_in[8];
    const float* ar2  = (const float*)d_in[9];
    const float* b2   = (const float*)d_in[10];
    float* out = (float*)d_out;

    char* w = (char*)d_ws;
    auto alloc = [&](size_t bytes) -> char* {
        char* p = w;
        w += (bytes + 255) & ~(size_t)255;
        return p;
    };
    int*   deg     = (int*)alloc((size_t)N_NODES * 4);
    int*   off     = (int*)alloc((size_t)(N_NODES + 1) * 4);
    int*   cursor  = (int*)alloc((size_t)N_NODES * 4);
    int*   part    = (int*)alloc((size_t)SCAN_P * 4);
    int*   pprefix = (int*)alloc((size_t)SCAN_P * 4);
    int*   csr_src = (int*)alloc((size_t)N_EDGES * 4);
    unsigned short* h1b = (unsigned short*)alloc((size_t)N_NODES * HD1 * 2);
    float* el1v    = (float*)alloc((size_t)N_NODES * HEADS * 4);
    float* er1v    = (float*)alloc((size_t)N_NODES * HEADS * 4);
    unsigned short* x2b = (unsigned short*)alloc((size_t)N_NODES * HD1 * 2);
    unsigned short* h2b = (unsigned short*)alloc((size_t)N_NODES * NC * 2);
    float* el2v    = (float*)alloc((size_t)N_NODES * 4);
    float* er2v    = (float*)alloc((size_t)N_NODES * 4);
    short* WTH     = (short*)alloc((size_t)F_IN * HD1 * 2);
    short* WTL     = (short*)alloc((size_t)F_IN * HD1 * 2);

    // CSR build
    k_zero<<<(N_NODES + 255) / 256, 256, 0, stream>>>(deg);
    k_count<<<(N_EDGES + 255) / 256, 256, 0, stream>>>(dst, deg);
    k_scan_partial<<<SCAN_P, 256, 0, stream>>>(deg, part);
    k_scan_mid<<<1, 128, 0, stream>>>(part, pprefix, off);
    k_scan_write<<<SCAN_P, 256, 0, stream>>>(deg, pprefix, off, cursor);
    k_scatter<<<(N_EDGES + 255) / 256, 256, 0, stream>>>(src, dst, cursor, csr_src);

    // Layer 1
    k_splitW<<<(F_IN * HD1 + 255) / 256, 256, 0, stream>>>(W1, WTH, WTL);
    dim3 g1((N_NODES + 127) / 128, 2);
    k_gemm1m<<<g1, 256, 0, stream>>>(feat, WTH, WTL, h1b);
    k_attn1<<<(N_NODES * HEADS + 255) / 256, 256, 0, stream>>>(h1b, al1, ar1, el1v, er1v);
    k_agg1<<<(N_NODES + 3) / 4, 256, 0, stream>>>(off, csr_src, el1v, er1v, h1b, b1, x2b);

    // Layer 2
    k_gemm2<<<1024, 256, 0, stream>>>(x2b, W2, al2, ar2, h2b, el2v, er2v);
    k_agg2<<<(N_NODES + 15) / 16, 256, 0, stream>>>(off, csr_src, el2v, er2v, h2b, b2, out);
}

// Round 4
// 374.352 us; speedup vs baseline: 2.0461x; 1.2560x over previous
//
#include <hip/hip_runtime.h>

#define N_NODES 100000
#define N_EDGES 1600000
#define F_IN 256
#define HD1 128   // HEADS*HID
#define HEADS 8
#define HID 16
#define NC 16
#define NEG_SLOPE 0.2f

__device__ __forceinline__ float leaky(float x){ return x > 0.f ? x : NEG_SLOPE * x; }
__device__ __forceinline__ unsigned short f2bf(float f){
    unsigned u = __float_as_uint(f);
    u += 0x7fff + ((u >> 16) & 1);       // round-to-nearest-even
    return (unsigned short)(u >> 16);
}
__device__ __forceinline__ float bf2f(unsigned short s){
    return __uint_as_float((unsigned)s << 16);
}

// fp32 -> OCP e4m3fn, RNE, clamp to +-448 (no inf/nan expected)
__device__ __forceinline__ unsigned char f2fp8(float x){
    unsigned u = __float_as_uint(x);
    unsigned sign = (u >> 24) & 0x80u;
    u &= 0x7fffffffu;
    if (u >= 0x43e00000u) u = 0x43e00000u;          // clamp |x| to 448
    float a = __uint_as_float(u);
    if (a < 0x1p-6f){                                // subnormal range
        int m = (int)rintf(a * 512.f);               // value = m * 2^-9, m in 0..8
        return (unsigned char)(sign | (unsigned)m);
    }
    unsigned lsb = (u >> 20) & 1u;
    u += 0x7ffffu + lsb;                             // RNE into 3 mantissa bits
    if (u > 0x43e00000u) u = 0x43e00000u;            // re-clamp post-round
    unsigned e8 = (u >> 23) - 120u;                  // exp-127+7
    unsigned m3 = (u >> 20) & 7u;
    return (unsigned char)(sign | (e8 << 3) | m3);
}

typedef __bf16 bf16x8 __attribute__((ext_vector_type(8)));
typedef short short8 __attribute__((ext_vector_type(8)));
typedef float f32x4 __attribute__((ext_vector_type(4)));

// ---------------- CSR build ----------------

__global__ void __launch_bounds__(256) k_count(const int* __restrict__ dst, int* __restrict__ deg){
    int i = blockIdx.x * 256 + threadIdx.x;
    if (i < N_EDGES) atomicAdd(&deg[dst[i]], 1);
}

#define SCAN_CHUNK 1024
#define SCAN_P ((N_NODES + SCAN_CHUNK - 1) / SCAN_CHUNK)   // 98

__global__ void __launch_bounds__(256) k_scan_partial(const int* __restrict__ deg, int* __restrict__ part){
    __shared__ int red[256];
    int t = threadIdx.x;
    int base = blockIdx.x * SCAN_CHUNK;
    int s = 0;
    for (int i = t; i < SCAN_CHUNK; i += 256){
        int idx = base + i;
        if (idx < N_NODES) s += deg[idx];
    }
    red[t] = s; __syncthreads();
    for (int o = 128; o > 0; o >>= 1){
        if (t < o) red[t] += red[t + o];
        __syncthreads();
    }
    if (t == 0) part[blockIdx.x] = red[0];
}

__global__ void __launch_bounds__(128) k_scan_mid(const int* __restrict__ part, int* __restrict__ pprefix, int* __restrict__ off){
    __shared__ int sd[128];
    int t = threadIdx.x;
    int v = (t < SCAN_P) ? part[t] : 0;
    sd[t] = v; __syncthreads();
    for (int o = 1; o < 128; o <<= 1){
        int add = (t >= o) ? sd[t - o] : 0;
        __syncthreads();
        sd[t] += add;
        __syncthreads();
    }
    if (t < SCAN_P) pprefix[t] = sd[t] - v;   // exclusive prefix of block totals
    if (t == 0) off[N_NODES] = N_EDGES;
}

__global__ void __launch_bounds__(256) k_scan_write(const int* __restrict__ deg, const int* __restrict__ pprefix,
                                                    int* __restrict__ off, int* __restrict__ cursor){
    __shared__ int sd[256];
    int t = threadIdx.x;
    int base = blockIdx.x * SCAN_CHUNK + t * 4;
    int v0 = 0, v1 = 0, v2 = 0, v3 = 0;
    if (base + 0 < N_NODES) v0 = deg[base + 0];
    if (base + 1 < N_NODES) v1 = deg[base + 1];
    if (base + 2 < N_NODES) v2 = deg[base + 2];
    if (base + 3 < N_NODES) v3 = deg[base + 3];
    int tsum = v0 + v1 + v2 + v3;
    sd[t] = tsum; __syncthreads();
    for (int o = 1; o < 256; o <<= 1){
        int add = (t >= o) ? sd[t - o] : 0;
        __syncthreads();
        sd[t] += add;
        __syncthreads();
    }
    int tpre = sd[t] - tsum + pprefix[blockIdx.x];
    int e0 = tpre, e1 = e0 + v0, e2 = e1 + v1, e3 = e2 + v2;
    if (base + 0 < N_NODES){ off[base + 0] = e0; cursor[base + 0] = e0; }
    if (base + 1 < N_NODES){ off[base + 1] = e1; cursor[base + 1] = e1; }
    if (base + 2 < N_NODES){ off[base + 2] = e2; cursor[base + 2] = e2; }
    if (base + 3 < N_NODES){ off[base + 3] = e3; cursor[base + 3] = e3; }
}

// scatter + per-edge attention weights w = exp(leaky(el1[s]+er1[d])) packed bf16x8
__global__ void __launch_bounds__(256) k_scatter(const int* __restrict__ src, const int* __restrict__ dst,
                                                 const float* __restrict__ el1, const float* __restrict__ er1,
                                                 int* __restrict__ cursor, int* __restrict__ csr_src,
                                                 unsigned short* __restrict__ wq){
    int i = blockIdx.x * 256 + threadIdx.x;
    if (i >= N_EDGES) return;
    int s = src[i], d = dst[i];
    int p = atomicAdd(&cursor[d], 1);
    csr_src[p] = s;
    const float4* elp = (const float4*)(el1 + (size_t)s * HEADS);
    const float4* erp = (const float4*)(er1 + (size_t)d * HEADS);
    float4 e0 = elp[0], e1 = elp[1];
    float4 r0 = erp[0], r1 = erp[1];
    ushort4 w0, w1;
    w0.x = f2bf(__expf(leaky(e0.x + r0.x)));
    w0.y = f2bf(__expf(leaky(e0.y + r0.y)));
    w0.z = f2bf(__expf(leaky(e0.z + r0.z)));
    w0.w = f2bf(__expf(leaky(e0.w + r0.w)));
    w1.x = f2bf(__expf(leaky(e1.x + r1.x)));
    w1.y = f2bf(__expf(leaky(e1.y + r1.y)));
    w1.z = f2bf(__expf(leaky(e1.z + r1.z)));
    w1.w = f2bf(__expf(leaky(e1.w + r1.w)));
    *(ushort4*)(wq + (size_t)p * 8) = w0;
    *(ushort4*)(wq + (size_t)p * 8 + 4) = w1;
}

// ---------------- W1 split (fp32 -> bf16 hi/lo), transpose + XOR-swizzle ----------------

__global__ void __launch_bounds__(256) k_splitW(const float* __restrict__ W1,
                                                short* __restrict__ WTH, short* __restrict__ WTL){
    int i = blockIdx.x * 256 + threadIdx.x;   // 32768 elems
    if (i >= F_IN * HD1) return;
    int k = i >> 7, n = i & 127;
    float v = W1[i];
    unsigned u = __float_as_uint(v);
    short hs = (short)(u >> 16);
    float lo = v - __uint_as_float(u & 0xffff0000u);
    short ls = (short)(__float_as_uint(lo) >> 16);
    int idx = n * 256 + (k ^ ((n & 7) << 3));
    WTH[idx] = hs;
    WTL[idx] = ls;
}

// ---------------- GEMM1 (MFMA bf16x2): h1b = bf16(feat @ W1), h1f8 = fp8(feat @ W1) ----------------

__device__ __forceinline__ void split8(float4 f0, float4 f1, short8& h, short8& l){
    float f[8] = {f0.x, f0.y, f0.z, f0.w, f1.x, f1.y, f1.z, f1.w};
    #pragma unroll
    for (int i = 0; i < 8; i++){
        unsigned u = __float_as_uint(f[i]);
        h[i] = (short)(u >> 16);
        float lo = f[i] - __uint_as_float(u & 0xffff0000u);
        l[i] = (short)(__float_as_uint(lo) >> 16);
    }
}

__global__ void __launch_bounds__(256, 2) k_gemm1m(const float* __restrict__ feat,
                                                   const short* __restrict__ WTH, const short* __restrict__ WTL,
                                                   unsigned short* __restrict__ h1b,
                                                   unsigned char* __restrict__ h1f8){
    __shared__ short sWH[64 * 256];
    __shared__ short sWL[64 * 256];
    int t = threadIdx.x;
    int ch = blockIdx.y;
    {
        const short8* gh = (const short8*)(WTH + (size_t)ch * 16384);
        const short8* gl = (const short8*)(WTL + (size_t)ch * 16384);
        short8* sh = (short8*)sWH;
        short8* sl = (short8*)sWL;
        for (int i = t; i < 2048; i += 256){ sh[i] = gh[i]; sl[i] = gl[i]; }
    }
    __syncthreads();

    int wid = t >> 6, lane = t & 63;
    int m16 = lane & 15, kg = lane >> 4;
    int rowb = blockIdx.x * 128 + wid * 32;

    f32x4 acc[2][4];
    #pragma unroll
    for (int a = 0; a < 2; a++)
        #pragma unroll
        for (int b = 0; b < 4; b++)
            acc[a][b] = (f32x4){0.f, 0.f, 0.f, 0.f};

    int r0 = rowb + m16;       if (r0 > N_NODES - 1) r0 = N_NODES - 1;
    int r1 = rowb + 16 + m16;  if (r1 > N_NODES - 1) r1 = N_NODES - 1;
    const float* fp0 = feat + (size_t)r0 * F_IN;
    const float* fp1 = feat + (size_t)r1 * F_IN;

    #pragma unroll
    for (int ks = 0; ks < 8; ks++){
        int kbase = ks * 32 + kg * 8;
        short8 ah[2], al[2];
        {
            const float4* p = (const float4*)(fp0 + kbase);
            split8(p[0], p[1], ah[0], al[0]);
        }
        {
            const float4* p = (const float4*)(fp1 + kbase);
            split8(p[0], p[1], ah[1], al[1]);
        }
        bf16x8 AH0 = __builtin_bit_cast(bf16x8, ah[0]);
        bf16x8 AH1 = __builtin_bit_cast(bf16x8, ah[1]);
        bf16x8 AL0 = __builtin_bit_cast(bf16x8, al[0]);
        bf16x8 AL1 = __builtin_bit_cast(bf16x8, al[1]);
        #pragma unroll
        for (int c = 0; c < 4; c++){
            int n = (c << 4) + m16;
            int kk = kbase ^ ((n & 7) << 3);
            bf16x8 bh = __builtin_bit_cast(bf16x8, *(const short8*)(sWH + n * 256 + kk));
            bf16x8 bl = __builtin_bit_cast(bf16x8, *(const short8*)(sWL + n * 256 + kk));
            acc[0][c] = __builtin_amdgcn_mfma_f32_16x16x32_bf16(AH0, bh, acc[0][c], 0, 0, 0);
            acc[1][c] = __builtin_amdgcn_mfma_f32_16x16x32_bf16(AH1, bh, acc[1][c], 0, 0, 0);
            acc[0][c] = __builtin_amdgcn_mfma_f32_16x16x32_bf16(AH0, bl, acc[0][c], 0, 0, 0);
            acc[1][c] = __builtin_amdgcn_mfma_f32_16x16x32_bf16(AH1, bl, acc[1][c], 0, 0, 0);
            acc[0][c] = __builtin_amdgcn_mfma_f32_16x16x32_bf16(AL0, bh, acc[0][c], 0, 0, 0);
            acc[1][c] = __builtin_amdgcn_mfma_f32_16x16x32_bf16(AL1, bh, acc[1][c], 0, 0, 0);
        }
    }

    #pragma unroll
    for (int rf = 0; rf < 2; rf++){
        #pragma unroll
        for (int c = 0; c < 4; c++){
            #pragma unroll
            for (int r = 0; r < 4; r++){
                int row = rowb + rf * 16 + kg * 4 + r;
                if (row < N_NODES){
                    float v = acc[rf][c][r];
                    int col = ch * 64 + c * 16 + m16;
                    h1b[(size_t)row * HD1 + col] = f2bf(v);
                    h1f8[(size_t)row * HD1 + col] = f2fp8(v);
                }
            }
        }
    }
}

// ---------------- el1/er1 from h1b ----------------

__global__ void __launch_bounds__(256) k_attn1(const unsigned short* __restrict__ h1b,
                                               const float* __restrict__ al1, const float* __restrict__ ar1,
                                               float* __restrict__ el1, float* __restrict__ er1){
    int i = blockIdx.x * 256 + threadIdx.x;
    if (i >= N_NODES * HEADS) return;
    int n = i >> 3, h = i & 7;
    const ushort4* hp = (const ushort4*)(h1b + (size_t)n * HD1 + h * HID);
    float pe = 0.f, pr = 0.f;
    #pragma unroll
    for (int j = 0; j < 4; j++){
        ushort4 v = hp[j];
        const float4 a = ((const float4*)(al1 + h * HID))[j];
        const float4 r = ((const float4*)(ar1 + h * HID))[j];
        float x0 = bf2f(v.x), x1 = bf2f(v.y), x2 = bf2f(v.z), x3 = bf2f(v.w);
        pe += x0 * a.x + x1 * a.y + x2 * a.z + x3 * a.w;
        pr += x0 * r.x + x1 * r.y + x2 * r.z + x3 * r.w;
    }
    el1[i] = pe;
    er1[i] = pr;
}

// ---------------- Layer-1 aggregation: one wave per dst node, 2 edges/iter, fp8 payload ----------------

__global__ void __launch_bounds__(256) k_agg1(const int* __restrict__ off, const int* __restrict__ csr_src,
                                              const unsigned short* __restrict__ wq,
                                              const unsigned char* __restrict__ h1f8,
                                              const float* __restrict__ b1,
                                              unsigned short* __restrict__ x2b){
    int wid = threadIdx.x >> 6, lane = threadIdx.x & 63;
    int n = blockIdx.x * 4 + wid;
    if (n >= N_NODES) return;
    int jb = off[n], je = off[n + 1];
    int q = lane & 31;
    int half = lane >> 5;
    int hh = q >> 2;                       // head for my 4 columns
    float acc0 = 0.f, acc1 = 0.f, acc2 = 0.f, acc3 = 0.f, wsum = 0.f;

    #pragma unroll 2
    for (int j = jb; j < je; j += 2){
        int j1 = (j + 1 < je) ? j + 1 : j;
        int jj = half ? j1 : j;
        int s = csr_src[jj];
        float wv = bf2f(wq[(size_t)jj * 8 + hh]);
        if (half && (j + 1 >= je)) wv = 0.f;
        unsigned u = *(const unsigned*)(h1f8 + (size_t)s * HD1 + q * 4);
        float v0 = __builtin_amdgcn_cvt_f32_fp8(u, 0);
        float v1 = __builtin_amdgcn_cvt_f32_fp8(u, 1);
        float v2 = __builtin_amdgcn_cvt_f32_fp8(u, 2);
        float v3 = __builtin_amdgcn_cvt_f32_fp8(u, 3);
        acc0 += wv * v0;
        acc1 += wv * v1;
        acc2 += wv * v2;
        acc3 += wv * v3;
        wsum += wv;
    }

    // combine halves
    acc0 += __shfl_xor(acc0, 32);
    acc1 += __shfl_xor(acc1, 32);
    acc2 += __shfl_xor(acc2, 32);
    acc3 += __shfl_xor(acc3, 32);
    wsum += __shfl_xor(wsum, 32);

    if (half == 0){
        float inv = (je > jb) ? 1.f / wsum : 0.f;
        float o0 = acc0 * inv, o1 = acc1 * inv, o2 = acc2 * inv, o3 = acc3 * inv;
        float4 bv = *(const float4*)(b1 + q * 4);
        o0 += bv.x; o1 += bv.y; o2 += bv.z; o3 += bv.w;
        o0 = o0 > 0.f ? o0 : __expf(o0) - 1.f;
        o1 = o1 > 0.f ? o1 : __expf(o1) - 1.f;
        o2 = o2 > 0.f ? o2 : __expf(o2) - 1.f;
        o3 = o3 > 0.f ? o3 : __expf(o3) - 1.f;
        ushort4 ov = { f2bf(o0), f2bf(o1), f2bf(o2), f2bf(o3) };
        *(ushort4*)(x2b + (size_t)n * HD1 + q * 4) = ov;
    }
}

// ---------------- GEMM2: h2b = bf16(x2 @ W2), fused el2/er2 ----------------

__global__ void __launch_bounds__(256) k_gemm2(const unsigned short* __restrict__ x2b, const float* __restrict__ W2,
                                               const float* __restrict__ al2, const float* __restrict__ ar2,
                                               unsigned short* __restrict__ h2b, float* __restrict__ el2, float* __restrict__ er2){
    __shared__ float sW[HD1 * NC];   // 8 KB
    __shared__ float sX[16 * HD1];   // 8 KB
    int t = threadIdx.x;
    for (int i = t; i < (HD1 * NC) / 4; i += 256)
        ((float4*)sW)[i] = ((const float4*)W2)[i];
    int r = t >> 4, c = t & 15;
    float a2 = al2[c], r2 = ar2[c];
    for (int g = blockIdx.x; g * 16 < N_NODES; g += gridDim.x){
        int rowb = g * 16;
        __syncthreads();
        {
            ushort4 v = ((const ushort4*)(x2b + (size_t)rowb * HD1))[t * 2];
            ushort4 v2 = ((const ushort4*)(x2b + (size_t)rowb * HD1))[t * 2 + 1];
            float4 f0 = { bf2f(v.x), bf2f(v.y), bf2f(v.z), bf2f(v.w) };
            float4 f1 = { bf2f(v2.x), bf2f(v2.y), bf2f(v2.z), bf2f(v2.w) };
            ((float4*)sX)[t * 2] = f0;
            ((float4*)sX)[t * 2 + 1] = f1;
        }
        __syncthreads();
        float acc = 0.f;
        #pragma unroll 8
        for (int k = 0; k < HD1; k++)
            acc += sX[r * HD1 + k] * sW[k * NC + c];
        int row = rowb + r;
        h2b[row * NC + c] = f2bf(acc);
        float pe = acc * a2, pr = acc * r2;
        #pragma unroll
        for (int d = 1; d < 16; d <<= 1){ pe += __shfl_xor(pe, d); pr += __shfl_xor(pr, d); }
        if (c == 0){ el2[row] = pe; er2[row] = pr; }
    }
}

// ---------------- Layer-2 aggregation + bias + log_softmax ----------------

__global__ void __launch_bounds__(256) k_agg2(const int* __restrict__ off, const int* __restrict__ csr_src,
                                              const float* __restrict__ el2, const float* __restrict__ er2,
                                              const unsigned short* __restrict__ h2b, const float* __restrict__ b2,
                                              float* __restrict__ out){
    int t = threadIdx.x;
    int sub = t >> 4;          // 16 nodes per block
    int c = t & 15;
    int n = blockIdx.x * 16 + sub;
    if (n >= N_NODES) return;
    int jb = off[n], je = off[n + 1];
    float er = er2[n];
    float accA = 0.f, accB = 0.f, wsA = 0.f, wsB = 0.f;
    int j = jb;
    for (; j + 1 < je; j += 2){
        int s0 = csr_src[j];
        int s1 = csr_src[j + 1];
        float w0 = __expf(leaky(el2[s0] + er));
        float w1 = __expf(leaky(el2[s1] + er));
        float v0 = bf2f(h2b[(size_t)s0 * NC + c]);
        float v1 = bf2f(h2b[(size_t)s1 * NC + c]);
        wsA += w0; accA += w0 * v0;
        wsB += w1; accB += w1 * v1;
    }
    if (j < je){
        int s0 = csr_src[j];
        float w0 = __expf(leaky(el2[s0] + er));
        wsA += w0; accA += w0 * bf2f(h2b[(size_t)s0 * NC + c]);
    }
    float acc = accA + accB, wsum = wsA + wsB;
    float o = (je > jb) ? acc / wsum : 0.f;
    o += b2[c];
    // log_softmax over the 16 classes (16-lane group)
    float m = o;
    #pragma unroll
    for (int d = 1; d < 16; d <<= 1) m = fmaxf(m, __shfl_xor(m, d));
    float ex = __expf(o - m);
    #pragma unroll
    for (int d = 1; d < 16; d <<= 1) ex += __shfl_xor(ex, d);
    out[(size_t)n * NC + c] = o - m - __logf(ex);
}

// ---------------- launch ----------------

extern "C" void kernel_launch(void* const* d_in, const int* in_sizes, int n_in,
                              void* d_out, int out_size, void* d_ws, size_t ws_size,
                              hipStream_t stream){
    const float* feat = (const float*)d_in[0];
    const int*   src  = (const int*)d_in[1];
    const int*   dst  = (const int*)d_in[2];
    const float* W1   = (const float*)d_in[3];
    const float* al1  = (const float*)d_in[4];
    const float* ar1  = (const float*)d_in[5];
    const float* b1   = (const float*)d_in[6];
    const float* W2   = (const float*)d_in[7];
    const float* al2  = (const float*)d_in[8];
    const float* ar2  = (const float*)d_in[9];
    const float* b2   = (const float*)d_in[10];
    float* out = (float*)d_out;

    char* w = (char*)d_ws;
    auto alloc = [&](size_t bytes) -> char* {
        char* p = w;
        w += (bytes + 255) & ~(size_t)255;
        return p;
    };
    int*   deg     = (int*)alloc((size_t)N_NODES * 4);
    int*   off     = (int*)alloc((size_t)(N_NODES + 1) * 4);
    int*   cursor  = (int*)alloc((size_t)N_NODES * 4);
    int*   part    = (int*)alloc((size_t)SCAN_P * 4);
    int*   pprefix = (int*)alloc((size_t)SCAN_P * 4);
    int*   csr_src = (int*)alloc((size_t)N_EDGES * 4);
    unsigned short* wq  = (unsigned short*)alloc((size_t)N_EDGES * HEADS * 2);
    unsigned short* h1b = (unsigned short*)alloc((size_t)N_NODES * HD1 * 2);
    unsigned char*  h1f8 = (unsigned char*)alloc((size_t)N_NODES * HD1);
    float* el1v    = (float*)alloc((size_t)N_NODES * HEADS * 4);
    float* er1v    = (float*)alloc((size_t)N_NODES * HEADS * 4);
    unsigned short* x2b = (unsigned short*)alloc((size_t)N_NODES * HD1 * 2);
    unsigned short* h2b = (unsigned short*)alloc((size_t)N_NODES * NC * 2);
    float* el2v    = (float*)alloc((size_t)N_NODES * 4);
    float* er2v    = (float*)alloc((size_t)N_NODES * 4);
    short* WTH     = (short*)alloc((size_t)F_IN * HD1 * 2);
    short* WTL     = (short*)alloc((size_t)F_IN * HD1 * 2);

    // CSR degree+scan (independent of layer-1 compute)
    hipMemsetAsync(deg, 0, (size_t)N_NODES * 4, stream);
    k_count<<<(N_EDGES + 255) / 256, 256, 0, stream>>>(dst, deg);
    k_scan_partial<<<SCAN_P, 256, 0, stream>>>(deg, part);
    k_scan_mid<<<1, 128, 0, stream>>>(part, pprefix, off);
    k_scan_write<<<SCAN_P, 256, 0, stream>>>(deg, pprefix, off, cursor);

    // Layer 1 compute
    k_splitW<<<(F_IN * HD1 + 255) / 256, 256, 0, stream>>>(W1, WTH, WTL);
    dim3 g1((N_NODES + 127) / 128, 2);
    k_gemm1m<<<g1, 256, 0, stream>>>(feat, WTH, WTL, h1b, h1f8);
    k_attn1<<<(N_NODES * HEADS + 255) / 256, 256, 0, stream>>>(h1b, al1, ar1, el1v, er1v);

    // scatter edges into CSR order + precompute softmax weights
    k_scatter<<<(N_EDGES + 255) / 256, 256, 0, stream>>>(src, dst, el1v, er1v, cursor, csr_src, wq);

    // Layer-1 aggregation
    k_agg1<<<(N_NODES + 3) / 4, 256, 0, stream>>>(off, csr_src, wq, h1f8, b1, x2b);

    // Layer 2
    k_gemm2<<<1024, 256, 0, stream>>>(x2b, W2, al2, ar2, h2b, el2v, er2v);
    k_agg2<<<(N_NODES + 15) / 16, 256, 0, stream>>>(off, csr_src, el2v, er2v, h2b, b2, out);
}